// Round 2
// baseline (282.604 us; speedup 1.0000x reference)
//
#include <hip/hip_runtime.h>
#include <cstdint>

constexpr int BTOT = 1048576;
constexpr int LCLS = 81;
constexpr int GRP  = 9;
constexpr int RPT  = 4;                     // rows per thread (keeps float4 16B-aligned)
constexpr int THR  = 256;
constexpr int NTHREAD = BTOT / RPT;         // 262144
constexpr int NBLK = NTHREAD / THR;         // 1024
constexpr float FIX = 67108864.0f;          // 2^26 fixed-point scale for loss

// Rare knife-edge path: recompute both argmaxes in f64 straight from global
// (rows are L1/L2-hot). Kept noinline so the big f64-exp blob stays out of
// the hot instruction stream.
__device__ __attribute__((noinline)) void refine_f64(
    const float* __restrict__ xrow, int& gi, int& wi)
{
    double dgs[GRP];
    #pragma unroll
    for (int g = 0; g < GRP; ++g) {
        double s = 0.0;
        #pragma unroll
        for (int j = 0; j < GRP; ++j) s += exp((double)xrow[g * GRP + j]);
        dgs[g] = s;
    }
    double dg1 = dgs[0]; int dgi = 0;
    #pragma unroll
    for (int g = 1; g < GRP; ++g) { if (dgs[g] > dg1) { dg1 = dgs[g]; dgi = g; } }
    double dw1 = exp((double)xrow[dgi * GRP]); int dwi = 0;
    #pragma unroll
    for (int j = 1; j < GRP; ++j) {
        double v = exp((double)xrow[dgi * GRP + j]);
        if (v > dw1) { dw1 = v; dwi = j; }
    }
    gi = dgi; wi = dwi;
}

__global__ __launch_bounds__(THR, 4) void hl_main(
    const float* __restrict__ x, const int* __restrict__ tgt,
    float* __restrict__ out, unsigned long long* __restrict__ part)
{
    const int tid  = blockIdx.x * THR + threadIdx.x;
    const size_t base = (size_t)tid * (RPT * LCLS);          // float index, 16B-aligned span
    const float4* p = reinterpret_cast<const float4*>(x + base);

    // ---- pass 1: stream 81 aligned float4, accumulate 4x9 group exp-sums ----
    float gs[RPT * GRP];
    #pragma unroll
    for (int i = 0; i < RPT * GRP; ++i) gs[i] = 0.0f;

    #pragma unroll
    for (int i = 0; i < (RPT * LCLS) / 4; ++i) {             // 81 float4 loads
        float4 v = p[i];
        const int e0 = 4 * i;
        gs[((e0 + 0) / LCLS) * GRP + ((e0 + 0) % LCLS) / GRP] += expf(v.x);
        gs[((e0 + 1) / LCLS) * GRP + ((e0 + 1) % LCLS) / GRP] += expf(v.y);
        gs[((e0 + 2) / LCLS) * GRP + ((e0 + 2) % LCLS) / GRP] += expf(v.z);
        gs[((e0 + 3) / LCLS) * GRP + ((e0 + 3) % LCLS) / GRP] += expf(v.w);
    }

    unsigned long long lq = 0;
    int dist = 0;

    // ---- pass 2: per row — argmaxes, loss term, pred store ----
    #pragma unroll
    for (int r = 0; r < RPT; ++r) {
        float S = gs[r * GRP];
        #pragma unroll
        for (int g = 1; g < GRP; ++g) S += gs[r * GRP + g];

        // group argmax with top-2 tracking (strict >, first index wins)
        float g1 = gs[r * GRP], g2 = -1e30f; int gi = 0;
        #pragma unroll
        for (int g = 1; g < GRP; ++g) {
            float v = gs[r * GRP + g];
            bool gt = v > g1;
            g2 = gt ? g1 : (v > g2 ? v : g2);
            g1 = gt ? v  : g1;
            gi = gt ? g  : gi;
        }

        const int row = tid * RPT + r;
        const int t = tgt[row];
        const int parent = t / GRP;

        float gpar = gs[r * GRP];
        #pragma unroll
        for (int g = 1; g < GRP; ++g)
            gpar = (parent == g) ? gs[r * GRP + g] : gpar;   // static-index select chain

        const float* xrow = x + base + r * LCLS;

        // within-group argmax with top-2 (re-read 9 floats: L1/L2-hot)
        const int wb = gi * GRP;
        float w1 = expf(xrow[wb]), w2 = -1e30f; int wi = 0;
        #pragma unroll
        for (int j = 1; j < GRP; ++j) {
            float v = expf(xrow[wb + j]);
            bool gt2 = v > w1;
            w2 = gt2 ? w1 : (v > w2 ? v : w2);
            w1 = gt2 ? v  : w1;
            wi = gt2 ? j  : wi;
        }

        if ((g1 - g2 < 1e-5f * g1) || (w1 - w2 < 1e-5f * w1))
            refine_f64(xrow, gi, wi);

        const int pred = gi * GRP + wi;

        float et  = expf(xrow[t]);
        float win = 0.5f * (gpar + et) / S;
        float nl  = -logf(win);
        lq   += (unsigned long long)llrintf(nl * FIX);
        dist += (pred == t) ? 0 : ((gi == parent) ? 1 : 2);

        out[1 + row] = (float)pred;
    }

    // ---- deterministic block reduction: fixed-point loss + int dist ----
    #pragma unroll
    for (int off = 32; off > 0; off >>= 1) {
        lq   += __shfl_down(lq, off);
        dist += __shfl_down(dist, off);
    }
    __shared__ unsigned long long redL[THR / 64];
    __shared__ unsigned long long redD[THR / 64];
    const int tl = threadIdx.x;
    if ((tl & 63) == 0) { redL[tl >> 6] = lq; redD[tl >> 6] = (unsigned long long)(unsigned)dist; }
    __syncthreads();
    if (tl == 0) {
        unsigned long long a = redL[0], b = redD[0];
        #pragma unroll
        for (int w = 1; w < THR / 64; ++w) { a += redL[w]; b += redD[w]; }
        part[blockIdx.x] = a;
        part[NBLK + blockIdx.x] = b;
    }
}

__global__ __launch_bounds__(256) void hl_final(
    const unsigned long long* __restrict__ part, float* __restrict__ out)
{
    const int tid = threadIdx.x;
    unsigned long long a = 0, b = 0;
    for (int i = tid; i < NBLK; i += 256) { a += part[i]; b += part[NBLK + i]; }
    #pragma unroll
    for (int off = 32; off > 0; off >>= 1) { a += __shfl_down(a, off); b += __shfl_down(b, off); }
    __shared__ unsigned long long rA[4], rB[4];
    if ((tid & 63) == 0) { rA[tid >> 6] = a; rB[tid >> 6] = b; }
    __syncthreads();
    if (tid == 0) {
        unsigned long long ta = 0, tb = 0;
        #pragma unroll
        for (int w = 0; w < 4; ++w) { ta += rA[w]; tb += rB[w]; }
        double loss = ((double)ta / 67108864.0) / (double)BTOT;
        out[0] = (float)loss;                  // -mean(log(win))
        out[1 + BTOT] = (float)tb;             // total_dist
    }
}

extern "C" void kernel_launch(void* const* d_in, const int* in_sizes, int n_in,
                              void* d_out, int out_size, void* d_ws, size_t ws_size,
                              hipStream_t stream) {
    const float* outputs = (const float*)d_in[0];
    const int*   target  = (const int*)d_in[1];
    float* out = (float*)d_out;
    unsigned long long* part = (unsigned long long*)d_ws;   // needs 2*1024*8 = 16,384 B

    hl_main<<<NBLK, THR, 0, stream>>>(outputs, target, out, part);
    hl_final<<<1, 256, 0, stream>>>(part, out);
}